// Round 1
// baseline (1138.629 us; speedup 1.0000x reference)
//
#include <hip/hip_runtime.h>
#include <math.h>

// ---------------------------------------------------------------------------
// GCN: 3x (GEMM -> normalized sparse aggregate (+self loop) -> bias -> tanh)
//      -> mean pool per graph -> linear head -> log_softmax
// Strategy: build CSR-by-dst once per launch (no atomics in hot aggregation),
// pull-based aggregation with one wave per node (64 lanes x float2 = 128 f).
// ---------------------------------------------------------------------------

// ---- degree histogram over dst (self-loops added analytically later) ------
__global__ void hist_dst(const int* __restrict__ dst, int* __restrict__ cnt, int E) {
    int e = blockIdx.x * 256 + threadIdx.x;
    if (e < E) atomicAdd(&cnt[dst[e]], 1);
}

// ---- dis[n] = rsqrt(deg[n]) with deg = in_cnt + 1 (self loop) -------------
__global__ void calc_dis(const int* __restrict__ cnt, float* __restrict__ dis, int n) {
    int i = blockIdx.x * 256 + threadIdx.x;
    if (i < n) dis[i] = rsqrtf((float)cnt[i] + 1.0f);
}

// ---- 3-kernel exclusive scan of cnt -> off (nblocks must be <= 256) -------
__global__ void scan_block(const int* __restrict__ cnt, int* __restrict__ off,
                           int* __restrict__ bsum, int n) {
    __shared__ int lds[256];
    int t = threadIdx.x;
    int i = blockIdx.x * 256 + t;
    int v = (i < n) ? cnt[i] : 0;
    lds[t] = v;
    __syncthreads();
    for (int d = 1; d < 256; d <<= 1) {
        int add = (t >= d) ? lds[t - d] : 0;
        __syncthreads();
        lds[t] += add;
        __syncthreads();
    }
    if (i < n) off[i] = lds[t] - v;           // exclusive within chunk
    if (t == 255) bsum[blockIdx.x] = lds[255]; // chunk total
}

__global__ void scan_top(const int* __restrict__ bsum, int* __restrict__ boff,
                         int* __restrict__ off, int nblocks, int n) {
    __shared__ int lds[256];
    int t = threadIdx.x;
    int v = (t < nblocks) ? bsum[t] : 0;
    lds[t] = v;
    __syncthreads();
    for (int d = 1; d < 256; d <<= 1) {
        int add = (t >= d) ? lds[t - d] : 0;
        __syncthreads();
        lds[t] += add;
        __syncthreads();
    }
    if (t < nblocks) boff[t] = lds[t] - v;    // exclusive block offsets
    if (t == 255) off[n] = lds[255];          // grand total = E
}

__global__ void scan_add(int* __restrict__ off, const int* __restrict__ boff, int n) {
    int i = blockIdx.x * 256 + threadIdx.x;
    if (i < n) off[i] += boff[blockIdx.x];
}

// ---- scatter edges into CSR slots (atomic cursor per dst) -----------------
__global__ void fill_csr(const int* __restrict__ src, const int* __restrict__ dst,
                         const float* __restrict__ dis, const int* __restrict__ off,
                         int* __restrict__ cursor, int* __restrict__ csr_src,
                         float* __restrict__ csr_w, int E) {
    int e = blockIdx.x * 256 + threadIdx.x;
    if (e >= E) return;
    int d = dst[e];
    int s = src[e];
    int p = off[d] + atomicAdd(&cursor[d], 1);
    csr_src[p] = s;
    csr_w[p] = dis[s];
}

// ---- GEMM: Cm[n x 128] = A[n x 128] @ W[128 x 128] ------------------------
// 256 threads: c = t&127, half = t>>7; 32 rows per block (16 per half).
// W staged in LDS in two 64-row chunks (32 KB) to keep occupancy up.
__global__ __launch_bounds__(256) void gemm128(const float* __restrict__ A,
                                               const float* __restrict__ W,
                                               float* __restrict__ Cm, int n) {
    __shared__ float Ws[64 * 128]; // 32 KB
    int t = threadIdx.x;
    int c = t & 127;
    int half = t >> 7;
    int row0 = blockIdx.x * 32 + half * 16;
    float acc[16];
#pragma unroll
    for (int i = 0; i < 16; ++i) acc[i] = 0.f;

    for (int kk = 0; kk < 128; kk += 64) {
        __syncthreads();
        for (int i = t; i < 64 * 128; i += 256)
            Ws[i] = W[(size_t)(kk + (i >> 7)) * 128 + (i & 127)];
        __syncthreads();
        if (row0 < n) {
#pragma unroll
            for (int rg = 0; rg < 16; rg += 4) {
                int r = row0 + rg;
                if (r >= n) break;
                const float* A0 = A + (size_t)r * 128 + kk;
                if (r + 4 <= n) {
#pragma unroll 8
                    for (int k = 0; k < 64; ++k) {
                        float w = Ws[(k << 7) + c];
                        acc[rg]     = fmaf(A0[k],       w, acc[rg]);
                        acc[rg + 1] = fmaf(A0[128 + k], w, acc[rg + 1]);
                        acc[rg + 2] = fmaf(A0[256 + k], w, acc[rg + 2]);
                        acc[rg + 3] = fmaf(A0[384 + k], w, acc[rg + 3]);
                    }
                } else {
                    for (int rr = 0; rr < 4 && r + rr < n; ++rr) {
                        float a = 0.f;
                        for (int k = 0; k < 64; ++k)
                            a = fmaf(A0[(size_t)rr * 128 + k], Ws[(k << 7) + c], a);
                        acc[rg + rr] += a;
                    }
                }
            }
        }
    }
    if (row0 < n) {
#pragma unroll
        for (int i = 0; i < 16; ++i) {
            int r = row0 + i;
            if (r < n) Cm[(size_t)r * 128 + c] = acc[i];
        }
    }
}

// ---- pull-based aggregation, fused self-loop + bias + tanh ----------------
// One wave per node (4 nodes per 256-thread block). lane handles feats 2l,2l+1.
__global__ __launch_bounds__(256) void aggregate(const float* __restrict__ h,
    const int* __restrict__ csr_src, const float* __restrict__ csr_w,
    const int* __restrict__ off, const float* __restrict__ dis,
    const float* __restrict__ bias, float* __restrict__ out, int n, int do_tanh) {
    int node = blockIdx.x * 4 + (threadIdx.x >> 6);
    if (node >= n) return;
    int lane = threadIdx.x & 63;

    int e0 = off[node];
    int e1 = off[node + 1];
    float accx = 0.f, accy = 0.f;
    for (int e = e0; e < e1; ++e) {
        int s = csr_src[e];
        float w = csr_w[e];
        const float2 v = *(const float2*)(h + (size_t)s * 128 + lane * 2);
        accx = fmaf(w, v.x, accx);
        accy = fmaf(w, v.y, accy);
    }
    float dn = dis[node];
    const float2 hv = *(const float2*)(h + (size_t)node * 128 + lane * 2);
    const float2 b  = *(const float2*)(bias + lane * 2);
    float ox = fmaf(dn, fmaf(dn, hv.x, accx), b.x);
    float oy = fmaf(dn, fmaf(dn, hv.y, accy), b.y);
    if (do_tanh) { ox = tanhf(ox); oy = tanhf(oy); }
    float2 o; o.x = ox; o.y = oy;
    *(float2*)(out + (size_t)node * 128 + lane * 2) = o;
}

// ---- per-graph node ranges via binary search on sorted batch --------------
__global__ void graph_starts(const int* __restrict__ batch, int* __restrict__ gstart,
                             int n, int G) {
    int g = blockIdx.x * 64 + threadIdx.x;
    if (g > G) return;
    int lo = 0, hi = n;
    while (lo < hi) {
        int mid = (lo + hi) >> 1;
        if (batch[mid] < g) lo = mid + 1; else hi = mid;
    }
    gstart[g] = lo;
}

// ---- mean pool: one block (wave) per graph --------------------------------
__global__ __launch_bounds__(64) void pool_mean(const float* __restrict__ act,
    const int* __restrict__ gstart, float* __restrict__ pooled, int G) {
    int g = blockIdx.x;
    int l = threadIdx.x;
    int lo = gstart[g], hi = gstart[g + 1];
    float accx = 0.f, accy = 0.f;
    for (int i = lo; i < hi; ++i) {
        const float2 v = *(const float2*)(act + (size_t)i * 128 + l * 2);
        accx += v.x;
        accy += v.y;
    }
    int cnt = hi - lo;
    float inv = 1.0f / (float)(cnt > 0 ? cnt : 1);
    pooled[(size_t)g * 128 + 2 * l]     = accx * inv;
    pooled[(size_t)g * 128 + 2 * l + 1] = accy * inv;
}

// ---- head: logits + log_softmax, one block per graph ----------------------
__global__ __launch_bounds__(64) void head_kernel(const float* __restrict__ pooled,
    const float* __restrict__ Wout, const float* __restrict__ bout,
    float* __restrict__ out, int C) {
    __shared__ float l[16];
    __shared__ float stats[2];
    int g = blockIdx.x;
    int t = threadIdx.x;
    if (t < C) {
        float acc = bout[t];
        for (int f = 0; f < 128; ++f)
            acc = fmaf(pooled[(size_t)g * 128 + f], Wout[(size_t)f * C + t], acc);
        l[t] = acc;
    }
    __syncthreads();
    if (t == 0) {
        float m = -1e30f;
        for (int c = 0; c < C; ++c) m = fmaxf(m, l[c]);
        float s = 0.f;
        for (int c = 0; c < C; ++c) s += expf(l[c] - m);
        stats[0] = m;
        stats[1] = logf(s);
    }
    __syncthreads();
    if (t < C) out[(size_t)g * C + t] = l[t] - stats[0] - stats[1];
}

// ---------------------------------------------------------------------------
extern "C" void kernel_launch(void* const* d_in, const int* in_sizes, int n_in,
                              void* d_out, int out_size, void* d_ws, size_t ws_size,
                              hipStream_t stream) {
    const float* x     = (const float*)d_in[0];
    const int*   edge  = (const int*)d_in[1];
    const int*   batch = (const int*)d_in[2];
    const float* W0 = (const float*)d_in[3];
    const float* b0 = (const float*)d_in[4];
    const float* W1 = (const float*)d_in[5];
    const float* b1 = (const float*)d_in[6];
    const float* W2 = (const float*)d_in[7];
    const float* b2 = (const float*)d_in[8];
    const float* Wout = (const float*)d_in[9];
    const float* bout = (const float*)d_in[10];
    float* out = (float*)d_out;

    const int N = in_sizes[0] / 128;   // 50000
    const int E = in_sizes[1] / 2;     // 1600000
    const int C = in_sizes[10];        // 10
    const int G = out_size / C;        // 512

    const int* src = edge;       // edge_index[0]
    const int* dst = edge + E;   // edge_index[1]

    // workspace carve-up (256B aligned)
    char* p = (char*)d_ws;
    auto alloc = [&](size_t bytes) -> void* {
        void* r = (void*)p;
        p += (bytes + 255) & ~(size_t)255;
        return r;
    };
    float* h      = (float*)alloc((size_t)N * 128 * 4);
    float* act    = (float*)alloc((size_t)N * 128 * 4);
    float* dis    = (float*)alloc((size_t)N * 4);
    int*   cnt    = (int*)alloc((size_t)N * 4);
    int*   cursor = (int*)alloc((size_t)N * 4);
    int*   off    = (int*)alloc((size_t)(N + 1) * 4);
    int*   bsum   = (int*)alloc(256 * 4);
    int*   boff   = (int*)alloc(256 * 4);
    int*   csr_src = (int*)alloc((size_t)E * 4);
    float* csr_w   = (float*)alloc((size_t)E * 4);
    int*   gstart  = (int*)alloc((size_t)(G + 1) * 4);
    float* pooled  = (float*)alloc((size_t)G * 128 * 4);

    hipMemsetAsync(cnt, 0, (size_t)N * 4, stream);
    hipMemsetAsync(cursor, 0, (size_t)N * 4, stream);

    const int eb = (E + 255) / 256;
    const int nb = (N + 255) / 256;   // 196 (<=256 required by scan_top)

    hist_dst<<<eb, 256, 0, stream>>>(dst, cnt, E);
    calc_dis<<<nb, 256, 0, stream>>>(cnt, dis, N);
    scan_block<<<nb, 256, 0, stream>>>(cnt, off, bsum, N);
    scan_top<<<1, 256, 0, stream>>>(bsum, boff, off, nb, N);
    scan_add<<<nb, 256, 0, stream>>>(off, boff, N);
    fill_csr<<<eb, 256, 0, stream>>>(src, dst, dis, off, cursor, csr_src, csr_w, E);

    const int gb = (N + 31) / 32;
    const int ab = (N + 3) / 4;

    gemm128<<<gb, 256, 0, stream>>>(x, W0, h, N);
    aggregate<<<ab, 256, 0, stream>>>(h, csr_src, csr_w, off, dis, b0, act, N, 1);
    gemm128<<<gb, 256, 0, stream>>>(act, W1, h, N);
    aggregate<<<ab, 256, 0, stream>>>(h, csr_src, csr_w, off, dis, b1, act, N, 1);
    gemm128<<<gb, 256, 0, stream>>>(act, W2, h, N);
    aggregate<<<ab, 256, 0, stream>>>(h, csr_src, csr_w, off, dis, b2, act, N, 0);

    graph_starts<<<(G + 64) / 64, 64, 0, stream>>>(batch, gstart, N, G);
    pool_mean<<<G, 64, 0, stream>>>(act, gstart, pooled, G);
    head_kernel<<<G, 64, 0, stream>>>(pooled, Wout, bout, out, C);
}

// Round 2
// 738.869 us; speedup vs baseline: 1.5410x; 1.5410x over previous
//
#include <hip/hip_runtime.h>
#include <math.h>

// ---------------------------------------------------------------------------
// GCN: 3x (GEMM(+dis scale) -> pull-aggregate (+self loop, bias, tanh))
//      -> mean pool -> head -> log_softmax
// R2: 128x128-tile GEMM with 8x8 register blocking (FMA:LDS = 64:4);
//     aggregate with 8-deep explicit gather pipeline; dis folded into GEMM
//     epilogue so aggregation is pure sums (no csr_w).
// ---------------------------------------------------------------------------

__global__ void hist_dst(const int* __restrict__ dst, int* __restrict__ cnt, int E) {
    int e = blockIdx.x * 256 + threadIdx.x;
    if (e < E) atomicAdd(&cnt[dst[e]], 1);
}

__global__ void calc_dis(const int* __restrict__ cnt, float* __restrict__ dis, int n) {
    int i = blockIdx.x * 256 + threadIdx.x;
    if (i < n) dis[i] = rsqrtf((float)cnt[i] + 1.0f);
}

// ---- 3-kernel exclusive scan of cnt -> off (nblocks must be <= 256) -------
__global__ void scan_block(const int* __restrict__ cnt, int* __restrict__ off,
                           int* __restrict__ bsum, int n) {
    __shared__ int lds[256];
    int t = threadIdx.x;
    int i = blockIdx.x * 256 + t;
    int v = (i < n) ? cnt[i] : 0;
    lds[t] = v;
    __syncthreads();
    for (int d = 1; d < 256; d <<= 1) {
        int add = (t >= d) ? lds[t - d] : 0;
        __syncthreads();
        lds[t] += add;
        __syncthreads();
    }
    if (i < n) off[i] = lds[t] - v;
    if (t == 255) bsum[blockIdx.x] = lds[255];
}

__global__ void scan_top(const int* __restrict__ bsum, int* __restrict__ boff,
                         int* __restrict__ off, int nblocks, int n) {
    __shared__ int lds[256];
    int t = threadIdx.x;
    int v = (t < nblocks) ? bsum[t] : 0;
    lds[t] = v;
    __syncthreads();
    for (int d = 1; d < 256; d <<= 1) {
        int add = (t >= d) ? lds[t - d] : 0;
        __syncthreads();
        lds[t] += add;
        __syncthreads();
    }
    if (t < nblocks) boff[t] = lds[t] - v;
    if (t == 255) off[n] = lds[255];
}

__global__ void scan_add(int* __restrict__ off, const int* __restrict__ boff, int n) {
    int i = blockIdx.x * 256 + threadIdx.x;
    if (i < n) off[i] += boff[blockIdx.x];
}

// ---- scatter edges into CSR slots (atomic cursor per dst) -----------------
__global__ void fill_csr(const int* __restrict__ src, const int* __restrict__ dst,
                         const int* __restrict__ off, int* __restrict__ cursor,
                         int* __restrict__ csr_src, int E) {
    int e = blockIdx.x * 256 + threadIdx.x;
    if (e >= E) return;
    int d = dst[e];
    int p = off[d] + atomicAdd(&cursor[d], 1);
    csr_src[p] = src[e];
}

// ---- GEMM: Hs[r] = dis[r] * (A[r] @ W),  A: n x 128, W: 128 x 128 ---------
// 128x128 tile per 256-thread block, 8x8 accumulator per thread.
// As k-major (transposed on stage) so per-k row reads are b128.
__global__ __launch_bounds__(256, 2) void gemm128v2(const float* __restrict__ A,
        const float* __restrict__ W, const float* __restrict__ dis,
        float* __restrict__ Hs, int n) {
    __shared__ float As[64 * 128];   // As[k*128 + r], 32 KB
    __shared__ float Ws[64 * 128];   // Ws[k*128 + c], 32 KB
    int t = threadIdx.x;
    int row0 = blockIdx.x * 128;
    int rg = (t & 15) * 8;           // 0..120
    int cg = (t >> 4) * 8;           // 0..120

    float acc[8][8];
#pragma unroll
    for (int i = 0; i < 8; ++i)
#pragma unroll
        for (int j = 0; j < 8; ++j) acc[i][j] = 0.f;

    for (int kk = 0; kk < 128; kk += 64) {
        __syncthreads();
        // stage A tile, transposed to k-major
        {
            int r = t & 127;
            int q = t >> 7;          // 0..1, each covers 32 k
            int grow = row0 + r;
            const float* Ap = A + (size_t)grow * 128 + kk + q * 32;
#pragma unroll
            for (int j = 0; j < 8; ++j) {
                float4 f;
                if (grow < n) f = ((const float4*)Ap)[j];
                else          f = float4{0.f, 0.f, 0.f, 0.f};
                int kb = q * 32 + j * 4;
                As[(kb + 0) * 128 + r] = f.x;
                As[(kb + 1) * 128 + r] = f.y;
                As[(kb + 2) * 128 + r] = f.z;
                As[(kb + 3) * 128 + r] = f.w;
            }
        }
        // stage W chunk (contiguous copy)
        {
            const float4* Wp = (const float4*)(W + (size_t)kk * 128);
            float4* Wl = (float4*)Ws;
            for (int i = t; i < 64 * 128 / 4; i += 256) Wl[i] = Wp[i];
        }
        __syncthreads();
#pragma unroll 4
        for (int k = 0; k < 64; ++k) {
            float4 a0 = *(const float4*)&As[k * 128 + rg];
            float4 a1 = *(const float4*)&As[k * 128 + rg + 4];
            float4 w0 = *(const float4*)&Ws[k * 128 + cg];
            float4 w1 = *(const float4*)&Ws[k * 128 + cg + 4];
            float a[8] = {a0.x, a0.y, a0.z, a0.w, a1.x, a1.y, a1.z, a1.w};
            float w[8] = {w0.x, w0.y, w0.z, w0.w, w1.x, w1.y, w1.z, w1.w};
#pragma unroll
            for (int i = 0; i < 8; ++i)
#pragma unroll
                for (int j = 0; j < 8; ++j)
                    acc[i][j] = fmaf(a[i], w[j], acc[i][j]);
        }
    }
    // epilogue: scale by dis[row], write
#pragma unroll
    for (int i = 0; i < 8; ++i) {
        int r = row0 + rg + i;
        if (r < n) {
            float d = dis[r];
            float4 o0 = {acc[i][0] * d, acc[i][1] * d, acc[i][2] * d, acc[i][3] * d};
            float4 o1 = {acc[i][4] * d, acc[i][5] * d, acc[i][6] * d, acc[i][7] * d};
            float* Op = Hs + (size_t)r * 128 + cg;
            *(float4*)Op = o0;
            *(float4*)(Op + 4) = o1;
        }
    }
}

// ---- pull aggregation: out[n] = tanh?(dn * (sum_s hs[s] + hs[n]) + bias) --
// hs rows are pre-scaled by dis[src]. One wave per node, 8-deep gather pipe.
__global__ __launch_bounds__(256) void aggregate(const float* __restrict__ hs,
    const int* __restrict__ csr_src, const int* __restrict__ off,
    const float* __restrict__ dis, const float* __restrict__ bias,
    float* __restrict__ out, int n, int do_tanh) {
    int node = blockIdx.x * 4 + (threadIdx.x >> 6);
    if (node >= n) return;
    int lane = threadIdx.x & 63;
    const float2* H = (const float2*)hs;

    int e0 = off[node];
    int e1 = off[node + 1];
    float ax0 = 0.f, ay0 = 0.f, ax1 = 0.f, ay1 = 0.f;
    int e = e0;
    for (; e + 8 <= e1; e += 8) {
        int s[8];
#pragma unroll
        for (int i = 0; i < 8; ++i) s[i] = csr_src[e + i];
        float2 v[8];
#pragma unroll
        for (int i = 0; i < 8; ++i) v[i] = H[(size_t)s[i] * 64 + lane];
#pragma unroll
        for (int i = 0; i < 8; i += 2) {
            ax0 += v[i].x;     ay0 += v[i].y;
            ax1 += v[i + 1].x; ay1 += v[i + 1].y;
        }
    }
    for (; e < e1; ++e) {
        int s = csr_src[e];
        float2 v = H[(size_t)s * 64 + lane];
        ax0 += v.x; ay0 += v.y;
    }
    float2 hv = H[(size_t)node * 64 + lane];   // self loop (pre-scaled by dn)
    float accx = ax0 + ax1 + hv.x;
    float accy = ay0 + ay1 + hv.y;
    float dn = dis[node];
    const float2 b = ((const float2*)bias)[lane];
    float ox = fmaf(dn, accx, b.x);
    float oy = fmaf(dn, accy, b.y);
    if (do_tanh) { ox = tanhf(ox); oy = tanhf(oy); }
    float2 o; o.x = ox; o.y = oy;
    *(float2*)(out + (size_t)node * 128 + lane * 2) = o;
}

// ---- per-graph node ranges via binary search on sorted batch --------------
__global__ void graph_starts(const int* __restrict__ batch, int* __restrict__ gstart,
                             int n, int G) {
    int g = blockIdx.x * 64 + threadIdx.x;
    if (g > G) return;
    int lo = 0, hi = n;
    while (lo < hi) {
        int mid = (lo + hi) >> 1;
        if (batch[mid] < g) lo = mid + 1; else hi = mid;
    }
    gstart[g] = lo;
}

__global__ __launch_bounds__(64) void pool_mean(const float* __restrict__ act,
    const int* __restrict__ gstart, float* __restrict__ pooled, int G) {
    int g = blockIdx.x;
    int l = threadIdx.x;
    int lo = gstart[g], hi = gstart[g + 1];
    float accx = 0.f, accy = 0.f;
    for (int i = lo; i < hi; ++i) {
        const float2 v = *(const float2*)(act + (size_t)i * 128 + l * 2);
        accx += v.x;
        accy += v.y;
    }
    int cnt = hi - lo;
    float inv = 1.0f / (float)(cnt > 0 ? cnt : 1);
    pooled[(size_t)g * 128 + 2 * l]     = accx * inv;
    pooled[(size_t)g * 128 + 2 * l + 1] = accy * inv;
}

__global__ __launch_bounds__(64) void head_kernel(const float* __restrict__ pooled,
    const float* __restrict__ Wout, const float* __restrict__ bout,
    float* __restrict__ out, int C) {
    __shared__ float l[16];
    __shared__ float stats[2];
    int g = blockIdx.x;
    int t = threadIdx.x;
    if (t < C) {
        float acc = bout[t];
        for (int f = 0; f < 128; ++f)
            acc = fmaf(pooled[(size_t)g * 128 + f], Wout[(size_t)f * C + t], acc);
        l[t] = acc;
    }
    __syncthreads();
    if (t == 0) {
        float m = -1e30f;
        for (int c = 0; c < C; ++c) m = fmaxf(m, l[c]);
        float s = 0.f;
        for (int c = 0; c < C; ++c) s += expf(l[c] - m);
        stats[0] = m;
        stats[1] = logf(s);
    }
    __syncthreads();
    if (t < C) out[(size_t)g * C + t] = l[t] - stats[0] - stats[1];
}

// ---------------------------------------------------------------------------
extern "C" void kernel_launch(void* const* d_in, const int* in_sizes, int n_in,
                              void* d_out, int out_size, void* d_ws, size_t ws_size,
                              hipStream_t stream) {
    const float* x     = (const float*)d_in[0];
    const int*   edge  = (const int*)d_in[1];
    const int*   batch = (const int*)d_in[2];
    const float* W0 = (const float*)d_in[3];
    const float* b0 = (const float*)d_in[4];
    const float* W1 = (const float*)d_in[5];
    const float* b1 = (const float*)d_in[6];
    const float* W2 = (const float*)d_in[7];
    const float* b2 = (const float*)d_in[8];
    const float* Wout = (const float*)d_in[9];
    const float* bout = (const float*)d_in[10];
    float* out = (float*)d_out;

    const int N = in_sizes[0] / 128;   // 50000
    const int E = in_sizes[1] / 2;     // 1600000
    const int C = in_sizes[10];        // 10
    const int G = out_size / C;        // 512

    const int* src = edge;
    const int* dst = edge + E;

    char* p = (char*)d_ws;
    auto alloc = [&](size_t bytes) -> void* {
        void* r = (void*)p;
        p += (bytes + 255) & ~(size_t)255;
        return r;
    };
    float* h      = (float*)alloc((size_t)N * 128 * 4);  // pre-scaled hs
    float* act    = (float*)alloc((size_t)N * 128 * 4);
    float* dis    = (float*)alloc((size_t)N * 4);
    int*   cnt    = (int*)alloc((size_t)N * 4);
    int*   cursor = (int*)alloc((size_t)N * 4);
    int*   off    = (int*)alloc((size_t)(N + 1) * 4);
    int*   bsum   = (int*)alloc(256 * 4);
    int*   boff   = (int*)alloc(256 * 4);
    int*   csr_src = (int*)alloc((size_t)E * 4);
    int*   gstart  = (int*)alloc((size_t)(G + 1) * 4);
    float* pooled  = (float*)alloc((size_t)G * 128 * 4);

    hipMemsetAsync(cnt, 0, (size_t)N * 4, stream);
    hipMemsetAsync(cursor, 0, (size_t)N * 4, stream);

    const int eb = (E + 255) / 256;
    const int nb = (N + 255) / 256;   // 196 (<=256 required by scan_top)

    hist_dst<<<eb, 256, 0, stream>>>(dst, cnt, E);
    calc_dis<<<nb, 256, 0, stream>>>(cnt, dis, N);
    scan_block<<<nb, 256, 0, stream>>>(cnt, off, bsum, N);
    scan_top<<<1, 256, 0, stream>>>(bsum, boff, off, nb, N);
    scan_add<<<nb, 256, 0, stream>>>(off, boff, N);
    fill_csr<<<eb, 256, 0, stream>>>(src, dst, off, cursor, csr_src, E);

    const int gb = (N + 127) / 128;
    const int ab = (N + 3) / 4;

    gemm128v2<<<gb, 256, 0, stream>>>(x,   W0, dis, h, N);
    aggregate<<<ab, 256, 0, stream>>>(h, csr_src, off, dis, b0, act, N, 1);
    gemm128v2<<<gb, 256, 0, stream>>>(act, W1, dis, h, N);
    aggregate<<<ab, 256, 0, stream>>>(h, csr_src, off, dis, b1, act, N, 1);
    gemm128v2<<<gb, 256, 0, stream>>>(act, W2, dis, h, N);
    aggregate<<<ab, 256, 0, stream>>>(h, csr_src, off, dis, b2, act, N, 0);

    graph_starts<<<(G + 64) / 64, 64, 0, stream>>>(batch, gstart, N, G);
    pool_mean<<<G, 64, 0, stream>>>(act, gstart, pooled, G);
    head_kernel<<<G, 64, 0, stream>>>(pooled, Wout, bout, out, C);
}